// Round 1
// baseline (733.509 us; speedup 1.0000x reference)
//
#include <hip/hip_runtime.h>
#include <math.h>

#define PI_F 3.14159265358979323846f

#define BATCH 4
#define CIN 256
#define CR 32
#define H0 224
#define HW0 (224*224)      // 50176
#define H1 111
#define HW1 (111*111)      // 12321
#define HS 35
#define HWS (35*35)        // 1225

// ---------------- Kernel 1: 1x1 reduce conv: x[4,256,224,224] -> c0[4,32,224,224]
__global__ __launch_bounds__(256) void k_conv1x1(
    const float* __restrict__ x, const float* __restrict__ w1,
    const float* __restrict__ b1, float* __restrict__ c0) {
  int pix = blockIdx.x * 256 + threadIdx.x;          // over B*HW0 = 200704
  if (pix >= BATCH * HW0) return;
  int b = pix / HW0, p = pix % HW0;
  const float* xb = x + (size_t)b * CIN * HW0 + p;
  float acc[CR];
#pragma unroll
  for (int o = 0; o < CR; ++o) acc[o] = b1[o];
  for (int c0i = 0; c0i < CIN; c0i += 8) {
    float xv[8];
#pragma unroll
    for (int j = 0; j < 8; ++j) xv[j] = xb[(size_t)(c0i + j) * HW0];
#pragma unroll
    for (int o = 0; o < CR; ++o) {
#pragma unroll
      for (int j = 0; j < 8; ++j)
        acc[o] = fmaf(xv[j], w1[o * CIN + c0i + j], acc[o]);
    }
  }
  float* ob = c0 + (size_t)b * CR * HW0 + p;
#pragma unroll
  for (int o = 0; o < CR; ++o) ob[(size_t)o * HW0] = acc[o];
}

// ---------------- Kernel 2: 3x3 stride2 pad0: c0 -> c1[4,32,111,111]
__global__ __launch_bounds__(256) void k_conv3x3s2(
    const float* __restrict__ c0, const float* __restrict__ wsw,
    const float* __restrict__ bs, float* __restrict__ c1) {
  int idx = blockIdx.x * 256 + threadIdx.x;          // over B*HW1
  if (idx >= BATCH * HW1) return;
  int b = idx / HW1, r = idx % HW1;
  int y = r / H1, xx = r % H1;
  const float* ibase = c0 + (size_t)b * CR * HW0;
  float acc[CR];
#pragma unroll
  for (int o = 0; o < CR; ++o) acc[o] = bs[o];
  for (int cb = 0; cb < CR; cb += 4) {
    float patch[36];
#pragma unroll
    for (int ci = 0; ci < 4; ++ci) {
      const float* ip = ibase + (size_t)(cb + ci) * HW0 + (2 * y) * H0 + 2 * xx;
#pragma unroll
      for (int ky = 0; ky < 3; ++ky)
#pragma unroll
        for (int kx = 0; kx < 3; ++kx)
          patch[ci * 9 + ky * 3 + kx] = ip[ky * H0 + kx];
    }
#pragma unroll
    for (int o = 0; o < CR; ++o) {
      float s = 0.f;
#pragma unroll
      for (int t = 0; t < 36; ++t)
        s = fmaf(patch[t], wsw[(o * CR + cb) * 9 + t], s);
      acc[o] += s;
    }
  }
  float* ob = c1 + (size_t)b * CR * HW1 + r;
#pragma unroll
  for (int o = 0; o < CR; ++o) ob[(size_t)o * HW1] = acc[o];
}

// ---------------- Kernel 3: maxpool 7x7 stride3 VALID: c1 -> pool[4,32,35,35]
__global__ __launch_bounds__(256) void k_maxpool(
    const float* __restrict__ c1, float* __restrict__ pool) {
  int idx = blockIdx.x * 256 + threadIdx.x;          // over B*CR*HWS
  if (idx >= BATCH * CR * HWS) return;
  int ch = idx / HWS, r = idx % HWS;
  int y = r / HS, x = r % HS;
  const float* ip = c1 + (size_t)ch * HW1 + (3 * y) * H1 + 3 * x;
  float m = -INFINITY;
#pragma unroll
  for (int ky = 0; ky < 7; ++ky)
#pragma unroll
    for (int kx = 0; kx < 7; ++kx)
      m = fmaxf(m, ip[ky * H1 + kx]);
  pool[idx] = m;
}

// ---------------- Kernel 4: FFT2 (row-col direct DFT) + fftshift + mask
// pool[img][35][35] -> hb (mag*mask, shifted), cph/sph (unit phase, shifted)
__global__ __launch_bounds__(256) void k_fft(
    const float* __restrict__ pool, float* __restrict__ hb,
    float* __restrict__ cph, float* __restrict__ sph) {
  __shared__ float p[HWS];
  __shared__ float Tr[HWS], Ti[HWS];
  __shared__ float twc[HS], tws[HS];
  int img = blockIdx.x;
  const float* ip = pool + (size_t)img * HWS;
  for (int i = threadIdx.x; i < HWS; i += 256) p[i] = ip[i];
  if (threadIdx.x < HS) {
    float ang = -2.f * PI_F * (float)threadIdx.x / (float)HS;
    twc[threadIdx.x] = cosf(ang);
    tws[threadIdx.x] = sinf(ang);
  }
  __syncthreads();
  // T[u][x] = sum_y p[y][x] e^{-2pi i u y/35}
  for (int i = threadIdx.x; i < HWS; i += 256) {
    int u = i / HS, xx = i % HS;
    float sr = 0.f, si = 0.f;
    int t = 0;
    for (int y = 0; y < HS; ++y) {
      float v = p[y * HS + xx];
      sr = fmaf(v, twc[t], sr);
      si = fmaf(v, tws[t], si);
      t += u; if (t >= HS) t -= HS;
    }
    Tr[i] = sr; Ti[i] = si;
  }
  __syncthreads();
  float* hp = hb + (size_t)img * HWS;
  float* cp = cph + (size_t)img * HWS;
  float* sp = sph + (size_t)img * HWS;
  for (int i = threadIdx.x; i < HWS; i += 256) {
    int oy = i / HS, ox = i % HS;
    int u = oy + 18; if (u >= HS) u -= HS;   // shifted[i] = F[(i-17)%35]
    int v = ox + 18; if (v >= HS) v -= HS;
    float fr = 0.f, fi = 0.f;
    int t = 0;
    for (int xx = 0; xx < HS; ++xx) {
      float tr = Tr[u * HS + xx], ti = Ti[u * HS + xx];
      float c = twc[t], s = tws[t];
      fr += tr * c - ti * s;
      fi += tr * s + ti * c;
      t += v; if (t >= HS) t -= HS;
    }
    float mag = sqrtf(fr * fr + fi * fi);
    float ic = 1.f, is = 0.f;
    if (mag > 0.f) { ic = fr / mag; is = fi / mag; }
    int dy = oy - 17, dx = ox - 17;
    float m = (dy * dy + dx * dx > 4) ? 1.f : 0.f;
    hp[i] = mag * m;
    cp[i] = ic; sp[i] = is;
  }
}

// ---------------- Kernel 5: fused DCN block: offsets conv + bilinear sample + einsum + ReLU
#define TPP 8
__global__ __launch_bounds__(256) void k_dcn(
    const float* __restrict__ hin, float* __restrict__ hout,
    const float* __restrict__ woff, const float* __restrict__ boff,
    const float* __restrict__ wreg, const float* __restrict__ breg) {
  __shared__ float wo[18 * CR * 9];
  __shared__ float wr[CR * CR * 9];
  __shared__ float bo[18], br[CR];
  for (int i = threadIdx.x; i < 18 * CR * 9; i += 256) wo[i] = woff[i];
  for (int i = threadIdx.x; i < CR * CR * 9; i += 256) wr[i] = wreg[i];
  if (threadIdx.x < 18) bo[threadIdx.x] = boff[threadIdx.x];
  if (threadIdx.x < CR) br[threadIdx.x] = breg[threadIdx.x];
  __syncthreads();
  int pg = threadIdx.x / TPP;
  int sub = threadIdx.x % TPP;
  int pid = blockIdx.x * (256 / TPP) + pg;           // over B*HWS = 4900
  bool active = pid < BATCH * HWS;
  int b = pid / HWS, r = pid % HWS;
  int y = r / HS, x = r % HS;
  const float* ib = hin + (size_t)b * CR * HWS;
  // Phase 1: offsets (each thread: 4 input channels)
  float off[18];
#pragma unroll
  for (int j = 0; j < 18; ++j) off[j] = 0.f;
  if (active) {
    for (int cc = 0; cc < 4; ++cc) {
      int ci = sub * 4 + cc;
      const float* ip = ib + (size_t)ci * HWS;
#pragma unroll
      for (int ky = 0; ky < 3; ++ky) {
        int yy = y + ky - 1;
        if (yy < 0 || yy > HS - 1) continue;
#pragma unroll
        for (int kx = 0; kx < 3; ++kx) {
          int xx = x + kx - 1;
          if (xx < 0 || xx > HS - 1) continue;
          float v = ip[yy * HS + xx];
#pragma unroll
          for (int j = 0; j < 18; ++j)
            off[j] = fmaf(v, wo[(j * CR + ci) * 9 + ky * 3 + kx], off[j]);
        }
      }
    }
  }
#pragma unroll
  for (int d = 1; d < TPP; d <<= 1)
#pragma unroll
    for (int j = 0; j < 18; ++j)
      off[j] += __shfl_xor(off[j], d);
#pragma unroll
  for (int j = 0; j < 18; ++j) off[j] += bo[j];
  // Phase 2: bilinear sampling + einsum partials
  float acc[CR];
#pragma unroll
  for (int o = 0; o < CR; ++o) acc[o] = 0.f;
  if (active) {
#pragma unroll
    for (int k = 0; k < 9; ++k) {
      int ky = k / 3, kx = k % 3;
      float ysf = (float)(y + ky - 1) + off[2 * k];
      float xsf = (float)(x + kx - 1) + off[2 * k + 1];
      float y0 = floorf(ysf), x0 = floorf(xsf);
      float fy = ysf - y0, fx = xsf - x0;
      float y1 = y0 + 1.f, x1 = x0 + 1.f;
      bool vy0 = (y0 >= 0.f) && (y0 <= 34.f);
      bool vy1 = (y1 >= 0.f) && (y1 <= 34.f);
      bool vx0 = (x0 >= 0.f) && (x0 <= 34.f);
      bool vx1 = (x1 >= 0.f) && (x1 <= 34.f);
      int iy0 = (int)fminf(fmaxf(y0, 0.f), 34.f);
      int iy1 = (int)fminf(fmaxf(y1, 0.f), 34.f);
      int ix0 = (int)fminf(fmaxf(x0, 0.f), 34.f);
      int ix1 = (int)fminf(fmaxf(x1, 0.f), 34.f);
      float w00 = (vy0 && vx0) ? (1.f - fy) * (1.f - fx) : 0.f;
      float w01 = (vy0 && vx1) ? (1.f - fy) * fx : 0.f;
      float w10 = (vy1 && vx0) ? fy * (1.f - fx) : 0.f;
      float w11 = (vy1 && vx1) ? fy * fx : 0.f;
      int i00 = iy0 * HS + ix0, i01 = iy0 * HS + ix1;
      int i10 = iy1 * HS + ix0, i11 = iy1 * HS + ix1;
#pragma unroll
      for (int cc = 0; cc < 4; ++cc) {
        int c = sub * 4 + cc;
        const float* ip = ib + (size_t)c * HWS;
        float s = w00 * ip[i00] + w01 * ip[i01] + w10 * ip[i10] + w11 * ip[i11];
#pragma unroll
        for (int o = 0; o < CR; ++o)
          acc[o] = fmaf(s, wr[(o * CR + c) * 9 + k], acc[o]);
      }
    }
  }
#pragma unroll
  for (int d = 1; d < TPP; d <<= 1)
#pragma unroll
    for (int o = 0; o < CR; ++o)
      acc[o] += __shfl_xor(acc[o], d);
  if (active) {
    float* ob = hout + (size_t)b * CR * HWS + r;
#pragma unroll
    for (int cc = 0; cc < 4; ++cc) {
      int o = sub * 4 + cc;
      float v = acc[o] + br[o];
      ob[(size_t)o * HWS] = fmaxf(v, 0.f);
    }
  }
}

// ---------------- Kernel 6: iFFT2 with ifftshift folded in; real part -> rec
__global__ __launch_bounds__(256) void k_ifft(
    const float* __restrict__ hb, const float* __restrict__ cph,
    const float* __restrict__ sph, float* __restrict__ rec) {
  __shared__ float Gr[HWS], Gi[HWS];
  __shared__ float Tr[HWS], Ti[HWS];
  __shared__ float twc[HS], tws[HS];
  int img = blockIdx.x;
  const float* hp = hb + (size_t)img * HWS;
  const float* cp = cph + (size_t)img * HWS;
  const float* sp = sph + (size_t)img * HWS;
  if (threadIdx.x < HS) {
    float ang = 2.f * PI_F * (float)threadIdx.x / (float)HS;
    twc[threadIdx.x] = cosf(ang);
    tws[threadIdx.x] = sinf(ang);
  }
  for (int i = threadIdx.x; i < HWS; i += 256) {
    int m = i / HS, n = i % HS;
    int sm = m + 17; if (sm >= HS) sm -= HS;   // ifftshift: G[m] = s[(m+17)%35]
    int sn = n + 17; if (sn >= HS) sn -= HS;
    int si = sm * HS + sn;
    float h = hp[si];
    Gr[i] = h * cp[si];
    Gi[i] = h * sp[si];
  }
  __syncthreads();
  // T2[y][v] = sum_u G[u][v] e^{+2pi i u y/35}
  for (int i = threadIdx.x; i < HWS; i += 256) {
    int yy = i / HS, v = i % HS;
    float sr = 0.f, sii = 0.f;
    int t = 0;
    for (int u = 0; u < HS; ++u) {
      float gr = Gr[u * HS + v], gi = Gi[u * HS + v];
      float c = twc[t], s = tws[t];
      sr += gr * c - gi * s;
      sii += gr * s + gi * c;
      t += yy; if (t >= HS) t -= HS;
    }
    Tr[i] = sr; Ti[i] = sii;
  }
  __syncthreads();
  float* rp = rec + (size_t)img * HWS;
  const float inv = 1.f / (float)(HWS);
  for (int i = threadIdx.x; i < HWS; i += 256) {
    int yy = i / HS, xx = i % HS;
    float sr = 0.f;
    int t = 0;
    for (int v = 0; v < HS; ++v) {
      sr += Tr[yy * HS + v] * twc[t] - Ti[yy * HS + v] * tws[t];
      t += xx; if (t >= HS) t -= HS;
    }
    rp[i] = sr * inv;
  }
}

// ---------------- Kernel 7: fused wb-matvec + bilinear upsample + w2-matvec + sigmoid gate
__global__ __launch_bounds__(256) void k_final(
    const float* __restrict__ x, const float* __restrict__ c0,
    const float* __restrict__ rec,
    const float* __restrict__ wb, const float* __restrict__ bb,
    const float* __restrict__ w2, const float* __restrict__ b2,
    float* __restrict__ out) {
  int pix = blockIdx.x * 256 + threadIdx.x;          // over B*HW0
  if (pix >= BATCH * HW0) return;
  int b = pix / HW0, p = pix % HW0;
  int h = p / H0, wcol = p % H0;
  const float* cb = c0 + (size_t)b * CR * HW0 + p;
  float cv[CR];
#pragma unroll
  for (int c = 0; c < CR; ++c) cv[c] = cb[(size_t)c * HW0];
  float v[CR];
#pragma unroll
  for (int cr = 0; cr < CR; ++cr) {
    float s = bb[cr];
#pragma unroll
    for (int c = 0; c < CR; ++c)
      s = fmaf(cv[c], wb[cr * CR + c], s);
    v[cr] = s;
  }
  // bilinear upsample from rec (align_corners=False, clamp-to-edge)
  const float scale = (float)HS / (float)H0;         // 35/224
  float sy = ((float)h + 0.5f) * scale - 0.5f;
  float sx = ((float)wcol + 0.5f) * scale - 0.5f;
  float y0f = floorf(sy), x0f = floorf(sx);
  float fy = sy - y0f, fx = sx - x0f;
  int y0 = max(0, min(HS - 1, (int)y0f));
  int y1 = max(0, min(HS - 1, (int)y0f + 1));
  int x0 = max(0, min(HS - 1, (int)x0f));
  int x1 = max(0, min(HS - 1, (int)x0f + 1));
  float w00 = (1.f - fy) * (1.f - fx), w01 = (1.f - fy) * fx;
  float w10 = fy * (1.f - fx), w11 = fy * fx;
  const float* rb = rec + (size_t)b * CR * HWS;
  int i00 = y0 * HS + x0, i01 = y0 * HS + x1, i10 = y1 * HS + x0, i11 = y1 * HS + x1;
#pragma unroll
  for (int cr = 0; cr < CR; ++cr) {
    const float* rp = rb + (size_t)cr * HWS;
    v[cr] += w00 * rp[i00] + w01 * rp[i01] + w10 * rp[i10] + w11 * rp[i11];
  }
  const float* xb = x + (size_t)b * CIN * HW0 + p;
  float* ob = out + (size_t)b * CIN * HW0 + p;
  for (int co = 0; co < CIN; ++co) {
    float s = b2[co];
#pragma unroll
    for (int cr = 0; cr < CR; ++cr)
      s = fmaf(v[cr], w2[co * CR + cr], s);
    float e = __expf(-s);
    float sg = __builtin_amdgcn_rcpf(1.f + e);
    ob[(size_t)co * HW0] = xb[(size_t)co * HW0] * sg;
  }
}

extern "C" void kernel_launch(void* const* d_in, const int* in_sizes, int n_in,
                              void* d_out, int out_size, void* d_ws, size_t ws_size,
                              hipStream_t stream) {
  const float* x    = (const float*)d_in[0];
  const float* w1   = (const float*)d_in[1];
  const float* b1   = (const float*)d_in[2];
  const float* wsw  = (const float*)d_in[3];
  const float* bs   = (const float*)d_in[4];
  const float* wb   = (const float*)d_in[5];
  const float* bb   = (const float*)d_in[6];
  const float* woff = (const float*)d_in[7];
  const float* boff = (const float*)d_in[8];
  const float* wreg = (const float*)d_in[9];
  const float* breg = (const float*)d_in[10];
  const float* w2   = (const float*)d_in[11];
  const float* b2   = (const float*)d_in[12];
  float* out = (float*)d_out;

  float* ws_f = (float*)d_ws;
  float* c0   = ws_f;                                    // 4*32*50176
  float* c1   = c0 + (size_t)BATCH * CR * HW0;           // 4*32*12321
  float* pool = c1 + (size_t)BATCH * CR * HW1;           // 4*32*1225
  float* hbA  = pool + (size_t)BATCH * CR * HWS;
  float* hbB  = hbA + (size_t)BATCH * CR * HWS;
  float* cph  = hbB + (size_t)BATCH * CR * HWS;
  float* sph  = cph + (size_t)BATCH * CR * HWS;
  float* rec  = sph + (size_t)BATCH * CR * HWS;

  k_conv1x1<<<(BATCH * HW0 + 255) / 256, 256, 0, stream>>>(x, w1, b1, c0);
  k_conv3x3s2<<<(BATCH * HW1 + 255) / 256, 256, 0, stream>>>(c0, wsw, bs, c1);
  k_maxpool<<<(BATCH * CR * HWS + 255) / 256, 256, 0, stream>>>(c1, pool);
  k_fft<<<BATCH * CR, 256, 0, stream>>>(pool, hbA, cph, sph);
  k_dcn<<<(BATCH * HWS + 31) / 32, 256, 0, stream>>>(hbA, hbB, woff, boff, wreg, breg);
  k_dcn<<<(BATCH * HWS + 31) / 32, 256, 0, stream>>>(hbB, hbA, woff + 5184, boff + 18, wreg + 9216, breg + 32);
  k_dcn<<<(BATCH * HWS + 31) / 32, 256, 0, stream>>>(hbA, hbB, woff + 2 * 5184, boff + 36, wreg + 2 * 9216, breg + 64);
  k_ifft<<<BATCH * CR, 256, 0, stream>>>(hbB, cph, sph, rec);
  k_final<<<(BATCH * HW0 + 255) / 256, 256, 0, stream>>>(x, c0, rec, wb, bb, w2, b2, out);
}

// Round 2
// 534.848 us; speedup vs baseline: 1.3714x; 1.3714x over previous
//
#include <hip/hip_runtime.h>
#include <math.h>

#define PI_F 3.14159265358979323846f

#define BATCH 4
#define CIN 256
#define CR 32
#define H0 224
#define HW0 (224*224)      // 50176
#define H1 111
#define HW1 (111*111)      // 12321
#define HS 35
#define HWS (35*35)        // 1225

// ---------------- Kernel 1: 1x1 reduce conv: x[4,256,224,224] -> c0[4,32,224,224]
__global__ __launch_bounds__(256) void k_conv1x1(
    const float* __restrict__ x, const float* __restrict__ w1,
    const float* __restrict__ b1, float* __restrict__ c0) {
  int pix = blockIdx.x * 256 + threadIdx.x;          // over B*HW0 = 200704 (exact multiple of 256)
  int b = pix / HW0, p = pix % HW0;
  const float* xb = x + (size_t)b * CIN * HW0 + p;
  float acc[CR];
#pragma unroll
  for (int o = 0; o < CR; ++o) acc[o] = b1[o];
  for (int c0i = 0; c0i < CIN; c0i += 8) {
    float xv[8];
#pragma unroll
    for (int j = 0; j < 8; ++j) xv[j] = xb[(size_t)(c0i + j) * HW0];
#pragma unroll
    for (int o = 0; o < CR; ++o) {
#pragma unroll
      for (int j = 0; j < 8; ++j)
        acc[o] = fmaf(xv[j], w1[o * CIN + c0i + j], acc[o]);
    }
  }
  float* ob = c0 + (size_t)b * CR * HW0 + p;
#pragma unroll
  for (int o = 0; o < CR; ++o) ob[(size_t)o * HW0] = acc[o];
}

// ---------------- Kernel 2: 3x3 stride2 pad0: c0 -> c1[4,32,111,111]
// thread = (pixel-pair along x, out-channel group of 8). 99456 threads.
#define PPR 56                       // pixel-pairs per output row
#define PAIRS_B (H1 * PPR)           // 6216
#define PAIRS_T (BATCH * PAIRS_B)    // 24864
#define C3_THREADS (PAIRS_T * 4)     // 99456
__global__ __launch_bounds__(256) void k_conv3x3s2(
    const float* __restrict__ c0, const float* __restrict__ wsw,
    const float* __restrict__ bs, float* __restrict__ c1) {
  __shared__ float wl[288 * 32];     // [ci*9+k][o] transposed weights, 36 KB
  int tid = threadIdx.x;
  for (int i = tid; i < 9216; i += 256) {
    int o = i & 31, r = i >> 5;
    wl[i] = wsw[o * 288 + r];
  }
  __syncthreads();
  int T = blockIdx.x * 256 + tid;
  if (T >= C3_THREADS) return;
  int og = T / PAIRS_T;
  int pair = T % PAIRS_T;
  int b = pair / PAIRS_B;
  int pr = pair % PAIRS_B;
  int y = pr / PPR, xp = pr % PPR;
  bool tail = (xp == PPR - 1);       // second pixel (x=111) invalid; col 4xp+4=224 OOB
  const float* ibase = c0 + (size_t)b * CR * HW0 + (2 * y) * H0 + 4 * xp;
  float acc0[8], acc1[8];
#pragma unroll
  for (int j = 0; j < 8; ++j) { acc0[j] = 0.f; acc1[j] = 0.f; }
  for (int ci = 0; ci < CR; ++ci) {
    float p[3][5];
#pragma unroll
    for (int ky = 0; ky < 3; ++ky) {
      const float* rp = ibase + (size_t)ci * HW0 + ky * H0;
      float4 v = *reinterpret_cast<const float4*>(rp);   // 4*xp is 16B-aligned
      p[ky][0] = v.x; p[ky][1] = v.y; p[ky][2] = v.z; p[ky][3] = v.w;
      p[ky][4] = tail ? 0.f : rp[4];
    }
    const float* wbase = &wl[ci * 9 * 32 + og * 8];
#pragma unroll
    for (int k = 0; k < 9; ++k) {
      int ky = k / 3, kx = k % 3;
      float4 wa = *reinterpret_cast<const float4*>(wbase + k * 32);
      float4 wc = *reinterpret_cast<const float4*>(wbase + k * 32 + 4);
      float wv[8] = {wa.x, wa.y, wa.z, wa.w, wc.x, wc.y, wc.z, wc.w};
      float pa = p[ky][kx], pb = p[ky][kx + 2];
#pragma unroll
      for (int j = 0; j < 8; ++j) {
        acc0[j] = fmaf(pa, wv[j], acc0[j]);
        acc1[j] = fmaf(pb, wv[j], acc1[j]);
      }
    }
  }
  float* ob = c1 + (size_t)b * CR * HW1 + y * H1 + 2 * xp;
  int o0 = og * 8;
#pragma unroll
  for (int j = 0; j < 8; ++j) {
    float bias = bs[o0 + j];
    ob[(size_t)(o0 + j) * HW1] = acc0[j] + bias;
    if (!tail) ob[(size_t)(o0 + j) * HW1 + 1] = acc1[j] + bias;
  }
}

// ---------------- Kernel 3: maxpool 7x7 stride3 VALID: c1 -> pool[4,32,35,35]
__global__ __launch_bounds__(256) void k_maxpool(
    const float* __restrict__ c1, float* __restrict__ pool) {
  int idx = blockIdx.x * 256 + threadIdx.x;          // over B*CR*HWS
  if (idx >= BATCH * CR * HWS) return;
  int ch = idx / HWS, r = idx % HWS;
  int y = r / HS, x = r % HS;
  const float* ip = c1 + (size_t)ch * HW1 + (3 * y) * H1 + 3 * x;
  float m = -INFINITY;
#pragma unroll
  for (int ky = 0; ky < 7; ++ky)
#pragma unroll
    for (int kx = 0; kx < 7; ++kx)
      m = fmaxf(m, ip[ky * H1 + kx]);
  pool[idx] = m;
}

// ---------------- Kernel 4: FFT2 (row-col direct DFT) + fftshift + mask
__global__ __launch_bounds__(256) void k_fft(
    const float* __restrict__ pool, float* __restrict__ hb,
    float* __restrict__ cph, float* __restrict__ sph) {
  __shared__ float p[HWS];
  __shared__ float Tr[HWS], Ti[HWS];
  __shared__ float twc[HS], tws[HS];
  int img = blockIdx.x;
  const float* ip = pool + (size_t)img * HWS;
  for (int i = threadIdx.x; i < HWS; i += 256) p[i] = ip[i];
  if (threadIdx.x < HS) {
    float ang = -2.f * PI_F * (float)threadIdx.x / (float)HS;
    twc[threadIdx.x] = cosf(ang);
    tws[threadIdx.x] = sinf(ang);
  }
  __syncthreads();
  for (int i = threadIdx.x; i < HWS; i += 256) {
    int u = i / HS, xx = i % HS;
    float sr = 0.f, si = 0.f;
    int t = 0;
    for (int y = 0; y < HS; ++y) {
      float v = p[y * HS + xx];
      sr = fmaf(v, twc[t], sr);
      si = fmaf(v, tws[t], si);
      t += u; if (t >= HS) t -= HS;
    }
    Tr[i] = sr; Ti[i] = si;
  }
  __syncthreads();
  float* hp = hb + (size_t)img * HWS;
  float* cp = cph + (size_t)img * HWS;
  float* sp = sph + (size_t)img * HWS;
  for (int i = threadIdx.x; i < HWS; i += 256) {
    int oy = i / HS, ox = i % HS;
    int u = oy + 18; if (u >= HS) u -= HS;
    int v = ox + 18; if (v >= HS) v -= HS;
    float fr = 0.f, fi = 0.f;
    int t = 0;
    for (int xx = 0; xx < HS; ++xx) {
      float tr = Tr[u * HS + xx], ti = Ti[u * HS + xx];
      float c = twc[t], s = tws[t];
      fr += tr * c - ti * s;
      fi += tr * s + ti * c;
      t += v; if (t >= HS) t -= HS;
    }
    float mag = sqrtf(fr * fr + fi * fi);
    float ic = 1.f, is = 0.f;
    if (mag > 0.f) { ic = fr / mag; is = fi / mag; }
    int dy = oy - 17, dx = ox - 17;
    float m = (dy * dy + dx * dx > 4) ? 1.f : 0.f;
    hp[i] = mag * m;
    cp[i] = ic; sp[i] = is;
  }
}

// ---------------- Kernel 5: fused DCN block
#define TPP 8
__global__ __launch_bounds__(256) void k_dcn(
    const float* __restrict__ hin, float* __restrict__ hout,
    const float* __restrict__ woff, const float* __restrict__ boff,
    const float* __restrict__ wreg, const float* __restrict__ breg) {
  __shared__ float wo[18 * CR * 9];
  __shared__ float wr[CR * CR * 9];
  __shared__ float bo[18], br[CR];
  for (int i = threadIdx.x; i < 18 * CR * 9; i += 256) wo[i] = woff[i];
  for (int i = threadIdx.x; i < CR * CR * 9; i += 256) wr[i] = wreg[i];
  if (threadIdx.x < 18) bo[threadIdx.x] = boff[threadIdx.x];
  if (threadIdx.x < CR) br[threadIdx.x] = breg[threadIdx.x];
  __syncthreads();
  int pg = threadIdx.x / TPP;
  int sub = threadIdx.x % TPP;
  int pid = blockIdx.x * (256 / TPP) + pg;
  bool active = pid < BATCH * HWS;
  int b = pid / HWS, r = pid % HWS;
  int y = r / HS, x = r % HS;
  const float* ib = hin + (size_t)b * CR * HWS;
  float off[18];
#pragma unroll
  for (int j = 0; j < 18; ++j) off[j] = 0.f;
  if (active) {
    for (int cc = 0; cc < 4; ++cc) {
      int ci = sub * 4 + cc;
      const float* ip = ib + (size_t)ci * HWS;
#pragma unroll
      for (int ky = 0; ky < 3; ++ky) {
        int yy = y + ky - 1;
        if (yy < 0 || yy > HS - 1) continue;
#pragma unroll
        for (int kx = 0; kx < 3; ++kx) {
          int xx = x + kx - 1;
          if (xx < 0 || xx > HS - 1) continue;
          float v = ip[yy * HS + xx];
#pragma unroll
          for (int j = 0; j < 18; ++j)
            off[j] = fmaf(v, wo[(j * CR + ci) * 9 + ky * 3 + kx], off[j]);
        }
      }
    }
  }
#pragma unroll
  for (int d = 1; d < TPP; d <<= 1)
#pragma unroll
    for (int j = 0; j < 18; ++j)
      off[j] += __shfl_xor(off[j], d);
#pragma unroll
  for (int j = 0; j < 18; ++j) off[j] += bo[j];
  float acc[CR];
#pragma unroll
  for (int o = 0; o < CR; ++o) acc[o] = 0.f;
  if (active) {
#pragma unroll
    for (int k = 0; k < 9; ++k) {
      int ky = k / 3, kx = k % 3;
      float ysf = (float)(y + ky - 1) + off[2 * k];
      float xsf = (float)(x + kx - 1) + off[2 * k + 1];
      float y0 = floorf(ysf), x0 = floorf(xsf);
      float fy = ysf - y0, fx = xsf - x0;
      float y1 = y0 + 1.f, x1 = x0 + 1.f;
      bool vy0 = (y0 >= 0.f) && (y0 <= 34.f);
      bool vy1 = (y1 >= 0.f) && (y1 <= 34.f);
      bool vx0 = (x0 >= 0.f) && (x0 <= 34.f);
      bool vx1 = (x1 >= 0.f) && (x1 <= 34.f);
      int iy0 = (int)fminf(fmaxf(y0, 0.f), 34.f);
      int iy1 = (int)fminf(fmaxf(y1, 0.f), 34.f);
      int ix0 = (int)fminf(fmaxf(x0, 0.f), 34.f);
      int ix1 = (int)fminf(fmaxf(x1, 0.f), 34.f);
      float w00 = (vy0 && vx0) ? (1.f - fy) * (1.f - fx) : 0.f;
      float w01 = (vy0 && vx1) ? (1.f - fy) * fx : 0.f;
      float w10 = (vy1 && vx0) ? fy * (1.f - fx) : 0.f;
      float w11 = (vy1 && vx1) ? fy * fx : 0.f;
      int i00 = iy0 * HS + ix0, i01 = iy0 * HS + ix1;
      int i10 = iy1 * HS + ix0, i11 = iy1 * HS + ix1;
#pragma unroll
      for (int cc = 0; cc < 4; ++cc) {
        int c = sub * 4 + cc;
        const float* ip = ib + (size_t)c * HWS;
        float s = w00 * ip[i00] + w01 * ip[i01] + w10 * ip[i10] + w11 * ip[i11];
#pragma unroll
        for (int o = 0; o < CR; ++o)
          acc[o] = fmaf(s, wr[(o * CR + c) * 9 + k], acc[o]);
      }
    }
  }
#pragma unroll
  for (int d = 1; d < TPP; d <<= 1)
#pragma unroll
    for (int o = 0; o < CR; ++o)
      acc[o] += __shfl_xor(acc[o], d);
  if (active) {
    float* ob = hout + (size_t)b * CR * HWS + r;
#pragma unroll
    for (int cc = 0; cc < 4; ++cc) {
      int o = sub * 4 + cc;
      float v = acc[o] + br[o];
      ob[(size_t)o * HWS] = fmaxf(v, 0.f);
    }
  }
}

// ---------------- Kernel 6: iFFT2 with ifftshift folded in
__global__ __launch_bounds__(256) void k_ifft(
    const float* __restrict__ hb, const float* __restrict__ cph,
    const float* __restrict__ sph, float* __restrict__ rec) {
  __shared__ float Gr[HWS], Gi[HWS];
  __shared__ float Tr[HWS], Ti[HWS];
  __shared__ float twc[HS], tws[HS];
  int img = blockIdx.x;
  const float* hp = hb + (size_t)img * HWS;
  const float* cp = cph + (size_t)img * HWS;
  const float* sp = sph + (size_t)img * HWS;
  if (threadIdx.x < HS) {
    float ang = 2.f * PI_F * (float)threadIdx.x / (float)HS;
    twc[threadIdx.x] = cosf(ang);
    tws[threadIdx.x] = sinf(ang);
  }
  for (int i = threadIdx.x; i < HWS; i += 256) {
    int m = i / HS, n = i % HS;
    int sm = m + 17; if (sm >= HS) sm -= HS;
    int sn = n + 17; if (sn >= HS) sn -= HS;
    int si = sm * HS + sn;
    float h = hp[si];
    Gr[i] = h * cp[si];
    Gi[i] = h * sp[si];
  }
  __syncthreads();
  for (int i = threadIdx.x; i < HWS; i += 256) {
    int yy = i / HS, v = i % HS;
    float sr = 0.f, sii = 0.f;
    int t = 0;
    for (int u = 0; u < HS; ++u) {
      float gr = Gr[u * HS + v], gi = Gi[u * HS + v];
      float c = twc[t], s = tws[t];
      sr += gr * c - gi * s;
      sii += gr * s + gi * c;
      t += yy; if (t >= HS) t -= HS;
    }
    Tr[i] = sr; Ti[i] = sii;
  }
  __syncthreads();
  float* rp = rec + (size_t)img * HWS;
  const float inv = 1.f / (float)(HWS);
  for (int i = threadIdx.x; i < HWS; i += 256) {
    int yy = i / HS, xx = i % HS;
    float sr = 0.f;
    int t = 0;
    for (int v = 0; v < HS; ++v) {
      sr += Tr[yy * HS + v] * twc[t] - Ti[yy * HS + v] * tws[t];
      t += xx; if (t >= HS) t -= HS;
    }
    rp[i] = sr * inv;
  }
}

// ---------------- Kernel 7: fused wb-matvec + upsample + w2-matvec + sigmoid gate
__global__ __launch_bounds__(256) void k_final(
    const float* __restrict__ x, const float* __restrict__ c0,
    const float* __restrict__ rec,
    const float* __restrict__ wb, const float* __restrict__ bb,
    const float* __restrict__ w2, const float* __restrict__ b2,
    float* __restrict__ out) {
  __shared__ float w2l[CIN * CR];    // 32 KB
  __shared__ float wbl[CR * CR];
  __shared__ float b2l[CIN], bbl[CR];
  int tid = threadIdx.x;
  for (int i = tid; i < CIN * CR; i += 256) w2l[i] = w2[i];
  for (int i = tid; i < CR * CR; i += 256) wbl[i] = wb[i];
  b2l[tid] = b2[tid];
  if (tid < CR) bbl[tid] = bb[tid];
  __syncthreads();
  int pix = blockIdx.x * 256 + tid;                 // over B*HW0 (exact)
  int b = pix / HW0, p = pix % HW0;
  int h = p / H0, wcol = p % H0;
  const float* cb = c0 + (size_t)b * CR * HW0 + p;
  float cv[CR];
#pragma unroll
  for (int c = 0; c < CR; ++c) cv[c] = cb[(size_t)c * HW0];
  float v[CR];
#pragma unroll
  for (int cr = 0; cr < CR; ++cr) {
    float s = bbl[cr];
    const float4* wrow = reinterpret_cast<const float4*>(&wbl[cr * CR]);
#pragma unroll
    for (int q = 0; q < 8; ++q) {
      float4 wv = wrow[q];
      s = fmaf(cv[4 * q], wv.x, s);
      s = fmaf(cv[4 * q + 1], wv.y, s);
      s = fmaf(cv[4 * q + 2], wv.z, s);
      s = fmaf(cv[4 * q + 3], wv.w, s);
    }
    v[cr] = s;
  }
  const float scale = (float)HS / (float)H0;
  float sy = ((float)h + 0.5f) * scale - 0.5f;
  float sx = ((float)wcol + 0.5f) * scale - 0.5f;
  float y0f = floorf(sy), x0f = floorf(sx);
  float fy = sy - y0f, fx = sx - x0f;
  int y0 = max(0, min(HS - 1, (int)y0f));
  int y1 = max(0, min(HS - 1, (int)y0f + 1));
  int x0 = max(0, min(HS - 1, (int)x0f));
  int x1 = max(0, min(HS - 1, (int)x0f + 1));
  float w00 = (1.f - fy) * (1.f - fx), w01 = (1.f - fy) * fx;
  float w10 = fy * (1.f - fx), w11 = fy * fx;
  const float* rb = rec + (size_t)b * CR * HWS;
  int i00 = y0 * HS + x0, i01 = y0 * HS + x1, i10 = y1 * HS + x0, i11 = y1 * HS + x1;
#pragma unroll
  for (int cr = 0; cr < CR; ++cr) {
    const float* rp = rb + (size_t)cr * HWS;
    v[cr] += w00 * rp[i00] + w01 * rp[i01] + w10 * rp[i10] + w11 * rp[i11];
  }
  const float* xb = x + (size_t)b * CIN * HW0 + p;
  float* ob = out + (size_t)b * CIN * HW0 + p;
  for (int co = 0; co < CIN; ++co) {
    float s = b2l[co];
    const float4* wrow = reinterpret_cast<const float4*>(&w2l[co * CR]);
#pragma unroll
    for (int q = 0; q < 8; ++q) {
      float4 wv = wrow[q];
      s = fmaf(v[4 * q], wv.x, s);
      s = fmaf(v[4 * q + 1], wv.y, s);
      s = fmaf(v[4 * q + 2], wv.z, s);
      s = fmaf(v[4 * q + 3], wv.w, s);
    }
    float e = __expf(-s);
    float sg = __builtin_amdgcn_rcpf(1.f + e);
    ob[(size_t)co * HW0] = xb[(size_t)co * HW0] * sg;
  }
}

extern "C" void kernel_launch(void* const* d_in, const int* in_sizes, int n_in,
                              void* d_out, int out_size, void* d_ws, size_t ws_size,
                              hipStream_t stream) {
  const float* x    = (const float*)d_in[0];
  const float* w1   = (const float*)d_in[1];
  const float* b1   = (const float*)d_in[2];
  const float* wsw  = (const float*)d_in[3];
  const float* bs   = (const float*)d_in[4];
  const float* wb   = (const float*)d_in[5];
  const float* bb   = (const float*)d_in[6];
  const float* woff = (const float*)d_in[7];
  const float* boff = (const float*)d_in[8];
  const float* wreg = (const float*)d_in[9];
  const float* breg = (const float*)d_in[10];
  const float* w2   = (const float*)d_in[11];
  const float* b2   = (const float*)d_in[12];
  float* out = (float*)d_out;

  float* ws_f = (float*)d_ws;
  float* c0   = ws_f;
  float* c1   = c0 + (size_t)BATCH * CR * HW0;
  float* pool = c1 + (size_t)BATCH * CR * HW1;
  float* hbA  = pool + (size_t)BATCH * CR * HWS;
  float* hbB  = hbA + (size_t)BATCH * CR * HWS;
  float* cph  = hbB + (size_t)BATCH * CR * HWS;
  float* sph  = cph + (size_t)BATCH * CR * HWS;
  float* rec  = sph + (size_t)BATCH * CR * HWS;

  k_conv1x1<<<(BATCH * HW0) / 256, 256, 0, stream>>>(x, w1, b1, c0);
  k_conv3x3s2<<<(C3_THREADS + 255) / 256, 256, 0, stream>>>(c0, wsw, bs, c1);
  k_maxpool<<<(BATCH * CR * HWS + 255) / 256, 256, 0, stream>>>(c1, pool);
  k_fft<<<BATCH * CR, 256, 0, stream>>>(pool, hbA, cph, sph);
  k_dcn<<<(BATCH * HWS + 31) / 32, 256, 0, stream>>>(hbA, hbB, woff, boff, wreg, breg);
  k_dcn<<<(BATCH * HWS + 31) / 32, 256, 0, stream>>>(hbB, hbA, woff + 5184, boff + 18, wreg + 9216, breg + 32);
  k_dcn<<<(BATCH * HWS + 31) / 32, 256, 0, stream>>>(hbA, hbB, woff + 2 * 5184, boff + 36, wreg + 2 * 9216, breg + 64);
  k_ifft<<<BATCH * CR, 256, 0, stream>>>(hbB, cph, sph, rec);
  k_final<<<(BATCH * HW0) / 256, 256, 0, stream>>>(x, c0, rec, wb, bb, w2, b2, out);
}

// Round 3
// 510.337 us; speedup vs baseline: 1.4373x; 1.0480x over previous
//
#include <hip/hip_runtime.h>
#include <math.h>

#define PI_F 3.14159265358979323846f

#define BATCH 4
#define CIN 256
#define CR 32
#define H0 224
#define HW0 (224*224)      // 50176
#define H1 111
#define HW1 (111*111)      // 12321
#define HS 35
#define HWS (35*35)        // 1225

// ---------------- Kernel 1: 1x1 reduce conv: x[4,256,224,224] -> c0[4,32,224,224]
// thread = 2 adjacent pixels, float2 I/O. 100352 threads, 784 blocks of 128.
__global__ __launch_bounds__(128) void k_conv1x1(
    const float* __restrict__ x, const float* __restrict__ w1,
    const float* __restrict__ b1, float* __restrict__ c0) {
  int t = blockIdx.x * 128 + threadIdx.x;            // over B*HW0/2
  int pp = t * 2;
  int b = pp / HW0, p = pp % HW0;
  const float* xb = x + (size_t)b * CIN * HW0 + p;
  float acc0[CR], acc1[CR];
#pragma unroll
  for (int o = 0; o < CR; ++o) { float bv = b1[o]; acc0[o] = bv; acc1[o] = bv; }
  for (int c = 0; c < CIN; c += 4) {
    float2 xv[4];
#pragma unroll
    for (int j = 0; j < 4; ++j)
      xv[j] = *reinterpret_cast<const float2*>(xb + (size_t)(c + j) * HW0);
#pragma unroll
    for (int o = 0; o < CR; ++o) {
#pragma unroll
      for (int j = 0; j < 4; ++j) {
        float w = w1[o * CIN + c + j];
        acc0[o] = fmaf(xv[j].x, w, acc0[o]);
        acc1[o] = fmaf(xv[j].y, w, acc1[o]);
      }
    }
  }
  float* ob = c0 + (size_t)b * CR * HW0 + p;
#pragma unroll
  for (int o = 0; o < CR; ++o) {
    float2 v2 = make_float2(acc0[o], acc1[o]);
    *reinterpret_cast<float2*>(ob + (size_t)o * HW0) = v2;
  }
}

// ---------------- Kernel 2: 3x3 stride2 pad0: c0 -> c1[4,32,111,111]
#define PPR 56
#define PAIRS_B (H1 * PPR)
#define PAIRS_T (BATCH * PAIRS_B)
#define C3_THREADS (PAIRS_T * 4)
__global__ __launch_bounds__(256) void k_conv3x3s2(
    const float* __restrict__ c0, const float* __restrict__ wsw,
    const float* __restrict__ bs, float* __restrict__ c1) {
  __shared__ float wl[288 * 32];
  int tid = threadIdx.x;
  for (int i = tid; i < 9216; i += 256) {
    int o = i & 31, r = i >> 5;
    wl[i] = wsw[o * 288 + r];
  }
  __syncthreads();
  int T = blockIdx.x * 256 + tid;
  if (T >= C3_THREADS) return;
  int og = T / PAIRS_T;
  int pair = T % PAIRS_T;
  int b = pair / PAIRS_B;
  int pr = pair % PAIRS_B;
  int y = pr / PPR, xp = pr % PPR;
  bool tail = (xp == PPR - 1);
  const float* ibase = c0 + (size_t)b * CR * HW0 + (2 * y) * H0 + 4 * xp;
  float acc0[8], acc1[8];
#pragma unroll
  for (int j = 0; j < 8; ++j) { acc0[j] = 0.f; acc1[j] = 0.f; }
  for (int ci = 0; ci < CR; ++ci) {
    float p[3][5];
#pragma unroll
    for (int ky = 0; ky < 3; ++ky) {
      const float* rp = ibase + (size_t)ci * HW0 + ky * H0;
      float4 v = *reinterpret_cast<const float4*>(rp);
      p[ky][0] = v.x; p[ky][1] = v.y; p[ky][2] = v.z; p[ky][3] = v.w;
      p[ky][4] = tail ? 0.f : rp[4];
    }
    const float* wbase = &wl[ci * 9 * 32 + og * 8];
#pragma unroll
    for (int k = 0; k < 9; ++k) {
      int ky = k / 3, kx = k % 3;
      float4 wa = *reinterpret_cast<const float4*>(wbase + k * 32);
      float4 wc = *reinterpret_cast<const float4*>(wbase + k * 32 + 4);
      float wv[8] = {wa.x, wa.y, wa.z, wa.w, wc.x, wc.y, wc.z, wc.w};
      float pa = p[ky][kx], pb = p[ky][kx + 2];
#pragma unroll
      for (int j = 0; j < 8; ++j) {
        acc0[j] = fmaf(pa, wv[j], acc0[j]);
        acc1[j] = fmaf(pb, wv[j], acc1[j]);
      }
    }
  }
  float* ob = c1 + (size_t)b * CR * HW1 + y * H1 + 2 * xp;
  int o0 = og * 8;
#pragma unroll
  for (int j = 0; j < 8; ++j) {
    float bias = bs[o0 + j];
    ob[(size_t)(o0 + j) * HW1] = acc0[j] + bias;
    if (!tail) ob[(size_t)(o0 + j) * HW1 + 1] = acc1[j] + bias;
  }
}

// ---------------- Kernel 3: maxpool 7x7 stride3 VALID
__global__ __launch_bounds__(256) void k_maxpool(
    const float* __restrict__ c1, float* __restrict__ pool) {
  int idx = blockIdx.x * 256 + threadIdx.x;
  if (idx >= BATCH * CR * HWS) return;
  int ch = idx / HWS, r = idx % HWS;
  int y = r / HS, x = r % HS;
  const float* ip = c1 + (size_t)ch * HW1 + (3 * y) * H1 + 3 * x;
  float m = -INFINITY;
#pragma unroll
  for (int ky = 0; ky < 7; ++ky)
#pragma unroll
    for (int kx = 0; kx < 7; ++kx)
      m = fmaxf(m, ip[ky * H1 + kx]);
  pool[idx] = m;
}

// ---------------- Kernel 4: FFT2 + fftshift + mask
__global__ __launch_bounds__(256) void k_fft(
    const float* __restrict__ pool, float* __restrict__ hb,
    float* __restrict__ cph, float* __restrict__ sph) {
  __shared__ float p[HWS];
  __shared__ float Tr[HWS], Ti[HWS];
  __shared__ float twc[HS], tws[HS];
  int img = blockIdx.x;
  const float* ip = pool + (size_t)img * HWS;
  for (int i = threadIdx.x; i < HWS; i += 256) p[i] = ip[i];
  if (threadIdx.x < HS) {
    float ang = -2.f * PI_F * (float)threadIdx.x / (float)HS;
    twc[threadIdx.x] = cosf(ang);
    tws[threadIdx.x] = sinf(ang);
  }
  __syncthreads();
  for (int i = threadIdx.x; i < HWS; i += 256) {
    int u = i / HS, xx = i % HS;
    float sr = 0.f, si = 0.f;
    int t = 0;
    for (int y = 0; y < HS; ++y) {
      float v = p[y * HS + xx];
      sr = fmaf(v, twc[t], sr);
      si = fmaf(v, tws[t], si);
      t += u; if (t >= HS) t -= HS;
    }
    Tr[i] = sr; Ti[i] = si;
  }
  __syncthreads();
  float* hp = hb + (size_t)img * HWS;
  float* cp = cph + (size_t)img * HWS;
  float* sp = sph + (size_t)img * HWS;
  for (int i = threadIdx.x; i < HWS; i += 256) {
    int oy = i / HS, ox = i % HS;
    int u = oy + 18; if (u >= HS) u -= HS;
    int v = ox + 18; if (v >= HS) v -= HS;
    float fr = 0.f, fi = 0.f;
    int t = 0;
    for (int xx = 0; xx < HS; ++xx) {
      float tr = Tr[u * HS + xx], ti = Ti[u * HS + xx];
      float c = twc[t], s = tws[t];
      fr += tr * c - ti * s;
      fi += tr * s + ti * c;
      t += v; if (t >= HS) t -= HS;
    }
    float mag = sqrtf(fr * fr + fi * fi);
    float ic = 1.f, is = 0.f;
    if (mag > 0.f) { ic = fr / mag; is = fi / mag; }
    int dy = oy - 17, dx = ox - 17;
    float m = (dy * dy + dx * dx > 4) ? 1.f : 0.f;
    hp[i] = mag * m;
    cp[i] = ic; sp[i] = is;
  }
}

// ---------------- Kernel 5: fused DCN block
#define TPP 8
__global__ __launch_bounds__(256) void k_dcn(
    const float* __restrict__ hin, float* __restrict__ hout,
    const float* __restrict__ woff, const float* __restrict__ boff,
    const float* __restrict__ wreg, const float* __restrict__ breg) {
  __shared__ float wo[18 * CR * 9];
  __shared__ float wr[CR * CR * 9];
  __shared__ float bo[18], br[CR];
  for (int i = threadIdx.x; i < 18 * CR * 9; i += 256) wo[i] = woff[i];
  for (int i = threadIdx.x; i < CR * CR * 9; i += 256) wr[i] = wreg[i];
  if (threadIdx.x < 18) bo[threadIdx.x] = boff[threadIdx.x];
  if (threadIdx.x < CR) br[threadIdx.x] = breg[threadIdx.x];
  __syncthreads();
  int pg = threadIdx.x / TPP;
  int sub = threadIdx.x % TPP;
  int pid = blockIdx.x * (256 / TPP) + pg;
  bool active = pid < BATCH * HWS;
  int b = pid / HWS, r = pid % HWS;
  int y = r / HS, x = r % HS;
  const float* ib = hin + (size_t)b * CR * HWS;
  float off[18];
#pragma unroll
  for (int j = 0; j < 18; ++j) off[j] = 0.f;
  if (active) {
    for (int cc = 0; cc < 4; ++cc) {
      int ci = sub * 4 + cc;
      const float* ip = ib + (size_t)ci * HWS;
#pragma unroll
      for (int ky = 0; ky < 3; ++ky) {
        int yy = y + ky - 1;
        if (yy < 0 || yy > HS - 1) continue;
#pragma unroll
        for (int kx = 0; kx < 3; ++kx) {
          int xx = x + kx - 1;
          if (xx < 0 || xx > HS - 1) continue;
          float v = ip[yy * HS + xx];
#pragma unroll
          for (int j = 0; j < 18; ++j)
            off[j] = fmaf(v, wo[(j * CR + ci) * 9 + ky * 3 + kx], off[j]);
        }
      }
    }
  }
#pragma unroll
  for (int d = 1; d < TPP; d <<= 1)
#pragma unroll
    for (int j = 0; j < 18; ++j)
      off[j] += __shfl_xor(off[j], d);
#pragma unroll
  for (int j = 0; j < 18; ++j) off[j] += bo[j];
  float acc[CR];
#pragma unroll
  for (int o = 0; o < CR; ++o) acc[o] = 0.f;
  if (active) {
#pragma unroll
    for (int k = 0; k < 9; ++k) {
      int ky = k / 3, kx = k % 3;
      float ysf = (float)(y + ky - 1) + off[2 * k];
      float xsf = (float)(x + kx - 1) + off[2 * k + 1];
      float y0 = floorf(ysf), x0 = floorf(xsf);
      float fy = ysf - y0, fx = xsf - x0;
      float y1 = y0 + 1.f, x1 = x0 + 1.f;
      bool vy0 = (y0 >= 0.f) && (y0 <= 34.f);
      bool vy1 = (y1 >= 0.f) && (y1 <= 34.f);
      bool vx0 = (x0 >= 0.f) && (x0 <= 34.f);
      bool vx1 = (x1 >= 0.f) && (x1 <= 34.f);
      int iy0 = (int)fminf(fmaxf(y0, 0.f), 34.f);
      int iy1 = (int)fminf(fmaxf(y1, 0.f), 34.f);
      int ix0 = (int)fminf(fmaxf(x0, 0.f), 34.f);
      int ix1 = (int)fminf(fmaxf(x1, 0.f), 34.f);
      float w00 = (vy0 && vx0) ? (1.f - fy) * (1.f - fx) : 0.f;
      float w01 = (vy0 && vx1) ? (1.f - fy) * fx : 0.f;
      float w10 = (vy1 && vx0) ? fy * (1.f - fx) : 0.f;
      float w11 = (vy1 && vx1) ? fy * fx : 0.f;
      int i00 = iy0 * HS + ix0, i01 = iy0 * HS + ix1;
      int i10 = iy1 * HS + ix0, i11 = iy1 * HS + ix1;
#pragma unroll
      for (int cc = 0; cc < 4; ++cc) {
        int c = sub * 4 + cc;
        const float* ip = ib + (size_t)c * HWS;
        float s = w00 * ip[i00] + w01 * ip[i01] + w10 * ip[i10] + w11 * ip[i11];
#pragma unroll
        for (int o = 0; o < CR; ++o)
          acc[o] = fmaf(s, wr[(o * CR + c) * 9 + k], acc[o]);
      }
    }
  }
#pragma unroll
  for (int d = 1; d < TPP; d <<= 1)
#pragma unroll
    for (int o = 0; o < CR; ++o)
      acc[o] += __shfl_xor(acc[o], d);
  if (active) {
    float* ob = hout + (size_t)b * CR * HWS + r;
#pragma unroll
    for (int cc = 0; cc < 4; ++cc) {
      int o = sub * 4 + cc;
      float v = acc[o] + br[o];
      ob[(size_t)o * HWS] = fmaxf(v, 0.f);
    }
  }
}

// ---------------- Kernel 6: iFFT2 with ifftshift folded in
__global__ __launch_bounds__(256) void k_ifft(
    const float* __restrict__ hb, const float* __restrict__ cph,
    const float* __restrict__ sph, float* __restrict__ rec) {
  __shared__ float Gr[HWS], Gi[HWS];
  __shared__ float Tr[HWS], Ti[HWS];
  __shared__ float twc[HS], tws[HS];
  int img = blockIdx.x;
  const float* hp = hb + (size_t)img * HWS;
  const float* cp = cph + (size_t)img * HWS;
  const float* sp = sph + (size_t)img * HWS;
  if (threadIdx.x < HS) {
    float ang = 2.f * PI_F * (float)threadIdx.x / (float)HS;
    twc[threadIdx.x] = cosf(ang);
    tws[threadIdx.x] = sinf(ang);
  }
  for (int i = threadIdx.x; i < HWS; i += 256) {
    int m = i / HS, n = i % HS;
    int sm = m + 17; if (sm >= HS) sm -= HS;
    int sn = n + 17; if (sn >= HS) sn -= HS;
    int si = sm * HS + sn;
    float h = hp[si];
    Gr[i] = h * cp[si];
    Gi[i] = h * sp[si];
  }
  __syncthreads();
  for (int i = threadIdx.x; i < HWS; i += 256) {
    int yy = i / HS, v = i % HS;
    float sr = 0.f, sii = 0.f;
    int t = 0;
    for (int u = 0; u < HS; ++u) {
      float gr = Gr[u * HS + v], gi = Gi[u * HS + v];
      float c = twc[t], s = tws[t];
      sr += gr * c - gi * s;
      sii += gr * s + gi * c;
      t += yy; if (t >= HS) t -= HS;
    }
    Tr[i] = sr; Ti[i] = sii;
  }
  __syncthreads();
  float* rp = rec + (size_t)img * HWS;
  const float inv = 1.f / (float)(HWS);
  for (int i = threadIdx.x; i < HWS; i += 256) {
    int yy = i / HS, xx = i % HS;
    float sr = 0.f;
    int t = 0;
    for (int v = 0; v < HS; ++v) {
      sr += Tr[yy * HS + v] * twc[t] - Ti[yy * HS + v] * tws[t];
      t += xx; if (t >= HS) t -= HS;
    }
    rp[i] = sr * inv;
  }
}

// ---------------- Kernel 7: fused gate. thread = 4 adjacent pixels (float4 I/O),
// block = 256 threads, co-chunk of 64. grid = 196 pixel-groups x 4 co-splits.
#define SSPLIT 4
#define COC (CIN / SSPLIT)         // 64
__global__ __launch_bounds__(256) void k_final(
    const float* __restrict__ x, const float* __restrict__ c0,
    const float* __restrict__ rec,
    const float* __restrict__ wb, const float* __restrict__ bb,
    const float* __restrict__ w2, const float* __restrict__ b2,
    float* __restrict__ out) {
  __shared__ float w2l[COC * CR];    // 8 KB: w2 rows for this co-chunk
  __shared__ float wblT[CR * CR];    // transposed wb: [c][cr]
  __shared__ float b2l[COC], bbl[CR];
  int tid = threadIdx.x;
  int pg = blockIdx.x / SSPLIT;
  int cs = blockIdx.x % SSPLIT;
  for (int i = tid; i < COC * CR; i += 256) w2l[i] = w2[cs * COC * CR + i];
  for (int i = tid; i < CR * CR; i += 256) {
    int c = i / CR, cr = i % CR;
    wblT[i] = wb[cr * CR + c];
  }
  if (tid < COC) b2l[tid] = b2[cs * COC + tid];
  if (tid < CR) bbl[tid] = bb[tid];
  __syncthreads();
  int gpix0 = pg * 1024 + tid * 4;                  // 4 adjacent pixels, one b
  int b = gpix0 / HW0, p0 = gpix0 % HW0;

  float v[4][CR];
  // --- upsample from rec + bias ---
  const float* rb = rec + (size_t)b * CR * HWS;
  const float scale = (float)HS / (float)H0;
#pragma unroll
  for (int px = 0; px < 4; ++px) {
    int p = p0 + px;
    int h = p / H0, wcol = p % H0;
    float sy = ((float)h + 0.5f) * scale - 0.5f;
    float sx = ((float)wcol + 0.5f) * scale - 0.5f;
    float y0f = floorf(sy), x0f = floorf(sx);
    float fy = sy - y0f, fx = sx - x0f;
    int y0 = max(0, min(HS - 1, (int)y0f));
    int y1 = max(0, min(HS - 1, (int)y0f + 1));
    int x0 = max(0, min(HS - 1, (int)x0f));
    int x1 = max(0, min(HS - 1, (int)x0f + 1));
    float w00 = (1.f - fy) * (1.f - fx), w01 = (1.f - fy) * fx;
    float w10 = fy * (1.f - fx), w11 = fy * fx;
    int i00 = y0 * HS + x0, i01 = y0 * HS + x1;
    int i10 = y1 * HS + x0, i11 = y1 * HS + x1;
#pragma unroll
    for (int cr = 0; cr < CR; ++cr) {
      const float* rp = rb + (size_t)cr * HWS;
      v[px][cr] = bbl[cr] + w00 * rp[i00] + w01 * rp[i01]
                + w10 * rp[i10] + w11 * rp[i11];
    }
  }
  // --- wb matvec from c0 (float4 per channel) ---
  const float* cb = c0 + (size_t)b * CR * HW0 + p0;
  for (int c = 0; c < CR; ++c) {
    float4 cv = *reinterpret_cast<const float4*>(cb + (size_t)c * HW0);
    const float4* wt = reinterpret_cast<const float4*>(&wblT[c * CR]);
#pragma unroll
    for (int q8 = 0; q8 < 8; ++q8) {
      float4 wv = wt[q8];
      v[0][q8 * 4 + 0] = fmaf(cv.x, wv.x, v[0][q8 * 4 + 0]);
      v[0][q8 * 4 + 1] = fmaf(cv.x, wv.y, v[0][q8 * 4 + 1]);
      v[0][q8 * 4 + 2] = fmaf(cv.x, wv.z, v[0][q8 * 4 + 2]);
      v[0][q8 * 4 + 3] = fmaf(cv.x, wv.w, v[0][q8 * 4 + 3]);
      v[1][q8 * 4 + 0] = fmaf(cv.y, wv.x, v[1][q8 * 4 + 0]);
      v[1][q8 * 4 + 1] = fmaf(cv.y, wv.y, v[1][q8 * 4 + 1]);
      v[1][q8 * 4 + 2] = fmaf(cv.y, wv.z, v[1][q8 * 4 + 2]);
      v[1][q8 * 4 + 3] = fmaf(cv.y, wv.w, v[1][q8 * 4 + 3]);
      v[2][q8 * 4 + 0] = fmaf(cv.z, wv.x, v[2][q8 * 4 + 0]);
      v[2][q8 * 4 + 1] = fmaf(cv.z, wv.y, v[2][q8 * 4 + 1]);
      v[2][q8 * 4 + 2] = fmaf(cv.z, wv.z, v[2][q8 * 4 + 2]);
      v[2][q8 * 4 + 3] = fmaf(cv.z, wv.w, v[2][q8 * 4 + 3]);
      v[3][q8 * 4 + 0] = fmaf(cv.w, wv.x, v[3][q8 * 4 + 0]);
      v[3][q8 * 4 + 1] = fmaf(cv.w, wv.y, v[3][q8 * 4 + 1]);
      v[3][q8 * 4 + 2] = fmaf(cv.w, wv.z, v[3][q8 * 4 + 2]);
      v[3][q8 * 4 + 3] = fmaf(cv.w, wv.w, v[3][q8 * 4 + 3]);
    }
  }
  // --- main co loop: dot(w2row, v) + sigmoid + gate ---
  const float* xb = x + ((size_t)b * CIN + cs * COC) * HW0 + p0;
  float* ob = out + ((size_t)b * CIN + cs * COC) * HW0 + p0;
  for (int j = 0; j < COC; ++j) {
    float4 wv[8];
    const float4* wrow = reinterpret_cast<const float4*>(&w2l[j * CR]);
#pragma unroll
    for (int q8 = 0; q8 < 8; ++q8) wv[q8] = wrow[q8];
    float bias = b2l[j];
    float4 x4 = *reinterpret_cast<const float4*>(xb + (size_t)j * HW0);
    float o4[4];
#pragma unroll
    for (int px = 0; px < 4; ++px) {
      float s0 = 0.f, s1 = 0.f;
#pragma unroll
      for (int q8 = 0; q8 < 8; ++q8) {
        s0 = fmaf(v[px][q8 * 4 + 0], wv[q8].x, s0);
        s1 = fmaf(v[px][q8 * 4 + 1], wv[q8].y, s1);
        s0 = fmaf(v[px][q8 * 4 + 2], wv[q8].z, s0);
        s1 = fmaf(v[px][q8 * 4 + 3], wv[q8].w, s1);
      }
      float s = bias + s0 + s1;
      float e = __expf(-s);
      o4[px] = __builtin_amdgcn_rcpf(1.f + e);
    }
    float4 r4 = make_float4(x4.x * o4[0], x4.y * o4[1], x4.z * o4[2], x4.w * o4[3]);
    *reinterpret_cast<float4*>(ob + (size_t)j * HW0) = r4;
  }
}

extern "C" void kernel_launch(void* const* d_in, const int* in_sizes, int n_in,
                              void* d_out, int out_size, void* d_ws, size_t ws_size,
                              hipStream_t stream) {
  const float* x    = (const float*)d_in[0];
  const float* w1   = (const float*)d_in[1];
  const float* b1   = (const float*)d_in[2];
  const float* wsw  = (const float*)d_in[3];
  const float* bs   = (const float*)d_in[4];
  const float* wb   = (const float*)d_in[5];
  const float* bb   = (const float*)d_in[6];
  const float* woff = (const float*)d_in[7];
  const float* boff = (const float*)d_in[8];
  const float* wreg = (const float*)d_in[9];
  const float* breg = (const float*)d_in[10];
  const float* w2   = (const float*)d_in[11];
  const float* b2   = (const float*)d_in[12];
  float* out = (float*)d_out;

  float* ws_f = (float*)d_ws;
  float* c0   = ws_f;
  float* c1   = c0 + (size_t)BATCH * CR * HW0;
  float* pool = c1 + (size_t)BATCH * CR * HW1;
  float* hbA  = pool + (size_t)BATCH * CR * HWS;
  float* hbB  = hbA + (size_t)BATCH * CR * HWS;
  float* cph  = hbB + (size_t)BATCH * CR * HWS;
  float* sph  = cph + (size_t)BATCH * CR * HWS;
  float* rec  = sph + (size_t)BATCH * CR * HWS;

  k_conv1x1<<<(BATCH * HW0 / 2) / 128, 128, 0, stream>>>(x, w1, b1, c0);
  k_conv3x3s2<<<(C3_THREADS + 255) / 256, 256, 0, stream>>>(c0, wsw, bs, c1);
  k_maxpool<<<(BATCH * CR * HWS + 255) / 256, 256, 0, stream>>>(c1, pool);
  k_fft<<<BATCH * CR, 256, 0, stream>>>(pool, hbA, cph, sph);
  k_dcn<<<(BATCH * HWS + 31) / 32, 256, 0, stream>>>(hbA, hbB, woff, boff, wreg, breg);
  k_dcn<<<(BATCH * HWS + 31) / 32, 256, 0, stream>>>(hbB, hbA, woff + 5184, boff + 18, wreg + 9216, breg + 32);
  k_dcn<<<(BATCH * HWS + 31) / 32, 256, 0, stream>>>(hbA, hbB, woff + 2 * 5184, boff + 36, wreg + 2 * 9216, breg + 64);
  k_ifft<<<BATCH * CR, 256, 0, stream>>>(hbB, cph, sph, rec);
  k_final<<<(BATCH * HW0 / 1024) * SSPLIT, 256, 0, stream>>>(x, c0, rec, wb, bb, w2, b2, out);
}

// Round 4
// 419.746 us; speedup vs baseline: 1.7475x; 1.2158x over previous
//
#include <hip/hip_runtime.h>
#include <math.h>

#define PI_F 3.14159265358979323846f

#define BATCH 4
#define CIN 256
#define CR 32
#define H0 224
#define HW0 (224*224)      // 50176
#define H1 111
#define HW1 (111*111)      // 12321
#define HS 35
#define HWS (35*35)        // 1225

// ---------------- Kernel 1: 1x1 reduce conv: x[4,256,224,224] -> c0[4,32,224,224]
__global__ __launch_bounds__(128) void k_conv1x1(
    const float* __restrict__ x, const float* __restrict__ w1,
    const float* __restrict__ b1, float* __restrict__ c0) {
  int t = blockIdx.x * 128 + threadIdx.x;            // over B*HW0/2
  int pp = t * 2;
  int b = pp / HW0, p = pp % HW0;
  const float* xb = x + (size_t)b * CIN * HW0 + p;
  float acc0[CR], acc1[CR];
#pragma unroll
  for (int o = 0; o < CR; ++o) { float bv = b1[o]; acc0[o] = bv; acc1[o] = bv; }
  for (int c = 0; c < CIN; c += 4) {
    float2 xv[4];
#pragma unroll
    for (int j = 0; j < 4; ++j)
      xv[j] = *reinterpret_cast<const float2*>(xb + (size_t)(c + j) * HW0);
#pragma unroll
    for (int o = 0; o < CR; ++o) {
#pragma unroll
      for (int j = 0; j < 4; ++j) {
        float w = w1[o * CIN + c + j];
        acc0[o] = fmaf(xv[j].x, w, acc0[o]);
        acc1[o] = fmaf(xv[j].y, w, acc1[o]);
      }
    }
  }
  float* ob = c0 + (size_t)b * CR * HW0 + p;
#pragma unroll
  for (int o = 0; o < CR; ++o) {
    float2 v2 = make_float2(acc0[o], acc1[o]);
    *reinterpret_cast<float2*>(ob + (size_t)o * HW0) = v2;
  }
}

// ---------------- Kernel 2: 3x3 stride2 pad0: c0 -> c1[4,32,111,111]
#define PPR 56
#define PAIRS_B (H1 * PPR)
#define PAIRS_T (BATCH * PAIRS_B)
#define C3_THREADS (PAIRS_T * 4)
__global__ __launch_bounds__(256) void k_conv3x3s2(
    const float* __restrict__ c0, const float* __restrict__ wsw,
    const float* __restrict__ bs, float* __restrict__ c1) {
  __shared__ float wl[288 * 32];
  int tid = threadIdx.x;
  for (int i = tid; i < 9216; i += 256) {
    int o = i & 31, r = i >> 5;
    wl[i] = wsw[o * 288 + r];
  }
  __syncthreads();
  int T = blockIdx.x * 256 + tid;
  if (T >= C3_THREADS) return;
  int og = T / PAIRS_T;
  int pair = T % PAIRS_T;
  int b = pair / PAIRS_B;
  int pr = pair % PAIRS_B;
  int y = pr / PPR, xp = pr % PPR;
  bool tail = (xp == PPR - 1);
  const float* ibase = c0 + (size_t)b * CR * HW0 + (2 * y) * H0 + 4 * xp;
  float acc0[8], acc1[8];
#pragma unroll
  for (int j = 0; j < 8; ++j) { acc0[j] = 0.f; acc1[j] = 0.f; }
  for (int ci = 0; ci < CR; ++ci) {
    float p[3][5];
#pragma unroll
    for (int ky = 0; ky < 3; ++ky) {
      const float* rp = ibase + (size_t)ci * HW0 + ky * H0;
      float4 v = *reinterpret_cast<const float4*>(rp);
      p[ky][0] = v.x; p[ky][1] = v.y; p[ky][2] = v.z; p[ky][3] = v.w;
      p[ky][4] = tail ? 0.f : rp[4];
    }
    const float* wbase = &wl[ci * 9 * 32 + og * 8];
#pragma unroll
    for (int k = 0; k < 9; ++k) {
      int ky = k / 3, kx = k % 3;
      float4 wa = *reinterpret_cast<const float4*>(wbase + k * 32);
      float4 wc = *reinterpret_cast<const float4*>(wbase + k * 32 + 4);
      float wv[8] = {wa.x, wa.y, wa.z, wa.w, wc.x, wc.y, wc.z, wc.w};
      float pa = p[ky][kx], pb = p[ky][kx + 2];
#pragma unroll
      for (int j = 0; j < 8; ++j) {
        acc0[j] = fmaf(pa, wv[j], acc0[j]);
        acc1[j] = fmaf(pb, wv[j], acc1[j]);
      }
    }
  }
  float* ob = c1 + (size_t)b * CR * HW1 + y * H1 + 2 * xp;
  int o0 = og * 8;
#pragma unroll
  for (int j = 0; j < 8; ++j) {
    float bias = bs[o0 + j];
    ob[(size_t)(o0 + j) * HW1] = acc0[j] + bias;
    if (!tail) ob[(size_t)(o0 + j) * HW1 + 1] = acc1[j] + bias;
  }
}

// ---------------- Kernel 3: maxpool 7x7 stride3 VALID
__global__ __launch_bounds__(256) void k_maxpool(
    const float* __restrict__ c1, float* __restrict__ pool) {
  int idx = blockIdx.x * 256 + threadIdx.x;
  if (idx >= BATCH * CR * HWS) return;
  int ch = idx / HWS, r = idx % HWS;
  int y = r / HS, x = r % HS;
  const float* ip = c1 + (size_t)ch * HW1 + (3 * y) * H1 + 3 * x;
  float m = -INFINITY;
#pragma unroll
  for (int ky = 0; ky < 7; ++ky)
#pragma unroll
    for (int kx = 0; kx < 7; ++kx)
      m = fmaxf(m, ip[ky * H1 + kx]);
  pool[idx] = m;
}

// ---------------- Kernel 4: FFT2 + fftshift + mask
__global__ __launch_bounds__(256) void k_fft(
    const float* __restrict__ pool, float* __restrict__ hb,
    float* __restrict__ cph, float* __restrict__ sph) {
  __shared__ float p[HWS];
  __shared__ float Tr[HWS], Ti[HWS];
  __shared__ float twc[HS], tws[HS];
  int img = blockIdx.x;
  const float* ip = pool + (size_t)img * HWS;
  for (int i = threadIdx.x; i < HWS; i += 256) p[i] = ip[i];
  if (threadIdx.x < HS) {
    float ang = -2.f * PI_F * (float)threadIdx.x / (float)HS;
    twc[threadIdx.x] = cosf(ang);
    tws[threadIdx.x] = sinf(ang);
  }
  __syncthreads();
  for (int i = threadIdx.x; i < HWS; i += 256) {
    int u = i / HS, xx = i % HS;
    float sr = 0.f, si = 0.f;
    int t = 0;
    for (int y = 0; y < HS; ++y) {
      float v = p[y * HS + xx];
      sr = fmaf(v, twc[t], sr);
      si = fmaf(v, tws[t], si);
      t += u; if (t >= HS) t -= HS;
    }
    Tr[i] = sr; Ti[i] = si;
  }
  __syncthreads();
  float* hp = hb + (size_t)img * HWS;
  float* cp = cph + (size_t)img * HWS;
  float* sp = sph + (size_t)img * HWS;
  for (int i = threadIdx.x; i < HWS; i += 256) {
    int oy = i / HS, ox = i % HS;
    int u = oy + 18; if (u >= HS) u -= HS;
    int v = ox + 18; if (v >= HS) v -= HS;
    float fr = 0.f, fi = 0.f;
    int t = 0;
    for (int xx = 0; xx < HS; ++xx) {
      float tr = Tr[u * HS + xx], ti = Ti[u * HS + xx];
      float c = twc[t], s = tws[t];
      fr += tr * c - ti * s;
      fi += tr * s + ti * c;
      t += v; if (t >= HS) t -= HS;
    }
    float mag = sqrtf(fr * fr + fi * fi);
    float ic = 1.f, is = 0.f;
    if (mag > 0.f) { ic = fr / mag; is = fi / mag; }
    int dy = oy - 17, dx = ox - 17;
    float m = (dy * dy + dx * dx > 4) ? 1.f : 0.f;
    hp[i] = mag * m;
    cp[i] = ic; sp[i] = is;
  }
}

// ---------------- Kernel 5: fused DCN block
#define TPP 8
__global__ __launch_bounds__(256) void k_dcn(
    const float* __restrict__ hin, float* __restrict__ hout,
    const float* __restrict__ woff, const float* __restrict__ boff,
    const float* __restrict__ wreg, const float* __restrict__ breg) {
  __shared__ float wo[18 * CR * 9];
  __shared__ float wr[CR * CR * 9];
  __shared__ float bo[18], br[CR];
  for (int i = threadIdx.x; i < 18 * CR * 9; i += 256) wo[i] = woff[i];
  for (int i = threadIdx.x; i < CR * CR * 9; i += 256) wr[i] = wreg[i];
  if (threadIdx.x < 18) bo[threadIdx.x] = boff[threadIdx.x];
  if (threadIdx.x < CR) br[threadIdx.x] = breg[threadIdx.x];
  __syncthreads();
  int pg = threadIdx.x / TPP;
  int sub = threadIdx.x % TPP;
  int pid = blockIdx.x * (256 / TPP) + pg;
  bool active = pid < BATCH * HWS;
  int b = pid / HWS, r = pid % HWS;
  int y = r / HS, x = r % HS;
  const float* ib = hin + (size_t)b * CR * HWS;
  float off[18];
#pragma unroll
  for (int j = 0; j < 18; ++j) off[j] = 0.f;
  if (active) {
    for (int cc = 0; cc < 4; ++cc) {
      int ci = sub * 4 + cc;
      const float* ip = ib + (size_t)ci * HWS;
#pragma unroll
      for (int ky = 0; ky < 3; ++ky) {
        int yy = y + ky - 1;
        if (yy < 0 || yy > HS - 1) continue;
#pragma unroll
        for (int kx = 0; kx < 3; ++kx) {
          int xx = x + kx - 1;
          if (xx < 0 || xx > HS - 1) continue;
          float v = ip[yy * HS + xx];
#pragma unroll
          for (int j = 0; j < 18; ++j)
            off[j] = fmaf(v, wo[(j * CR + ci) * 9 + ky * 3 + kx], off[j]);
        }
      }
    }
  }
#pragma unroll
  for (int d = 1; d < TPP; d <<= 1)
#pragma unroll
    for (int j = 0; j < 18; ++j)
      off[j] += __shfl_xor(off[j], d);
#pragma unroll
  for (int j = 0; j < 18; ++j) off[j] += bo[j];
  float acc[CR];
#pragma unroll
  for (int o = 0; o < CR; ++o) acc[o] = 0.f;
  if (active) {
#pragma unroll
    for (int k = 0; k < 9; ++k) {
      int ky = k / 3, kx = k % 3;
      float ysf = (float)(y + ky - 1) + off[2 * k];
      float xsf = (float)(x + kx - 1) + off[2 * k + 1];
      float y0 = floorf(ysf), x0 = floorf(xsf);
      float fy = ysf - y0, fx = xsf - x0;
      float y1 = y0 + 1.f, x1 = x0 + 1.f;
      bool vy0 = (y0 >= 0.f) && (y0 <= 34.f);
      bool vy1 = (y1 >= 0.f) && (y1 <= 34.f);
      bool vx0 = (x0 >= 0.f) && (x0 <= 34.f);
      bool vx1 = (x1 >= 0.f) && (x1 <= 34.f);
      int iy0 = (int)fminf(fmaxf(y0, 0.f), 34.f);
      int iy1 = (int)fminf(fmaxf(y1, 0.f), 34.f);
      int ix0 = (int)fminf(fmaxf(x0, 0.f), 34.f);
      int ix1 = (int)fminf(fmaxf(x1, 0.f), 34.f);
      float w00 = (vy0 && vx0) ? (1.f - fy) * (1.f - fx) : 0.f;
      float w01 = (vy0 && vx1) ? (1.f - fy) * fx : 0.f;
      float w10 = (vy1 && vx0) ? fy * (1.f - fx) : 0.f;
      float w11 = (vy1 && vx1) ? fy * fx : 0.f;
      int i00 = iy0 * HS + ix0, i01 = iy0 * HS + ix1;
      int i10 = iy1 * HS + ix0, i11 = iy1 * HS + ix1;
#pragma unroll
      for (int cc = 0; cc < 4; ++cc) {
        int c = sub * 4 + cc;
        const float* ip = ib + (size_t)c * HWS;
        float s = w00 * ip[i00] + w01 * ip[i01] + w10 * ip[i10] + w11 * ip[i11];
#pragma unroll
        for (int o = 0; o < CR; ++o)
          acc[o] = fmaf(s, wr[(o * CR + c) * 9 + k], acc[o]);
      }
    }
  }
#pragma unroll
  for (int d = 1; d < TPP; d <<= 1)
#pragma unroll
    for (int o = 0; o < CR; ++o)
      acc[o] += __shfl_xor(acc[o], d);
  if (active) {
    float* ob = hout + (size_t)b * CR * HWS + r;
#pragma unroll
    for (int cc = 0; cc < 4; ++cc) {
      int o = sub * 4 + cc;
      float v = acc[o] + br[o];
      ob[(size_t)o * HWS] = fmaxf(v, 0.f);
    }
  }
}

// ---------------- Kernel 6: iFFT2 with ifftshift folded in
__global__ __launch_bounds__(256) void k_ifft(
    const float* __restrict__ hb, const float* __restrict__ cph,
    const float* __restrict__ sph, float* __restrict__ rec) {
  __shared__ float Gr[HWS], Gi[HWS];
  __shared__ float Tr[HWS], Ti[HWS];
  __shared__ float twc[HS], tws[HS];
  int img = blockIdx.x;
  const float* hp = hb + (size_t)img * HWS;
  const float* cp = cph + (size_t)img * HWS;
  const float* sp = sph + (size_t)img * HWS;
  if (threadIdx.x < HS) {
    float ang = 2.f * PI_F * (float)threadIdx.x / (float)HS;
    twc[threadIdx.x] = cosf(ang);
    tws[threadIdx.x] = sinf(ang);
  }
  for (int i = threadIdx.x; i < HWS; i += 256) {
    int m = i / HS, n = i % HS;
    int sm = m + 17; if (sm >= HS) sm -= HS;
    int sn = n + 17; if (sn >= HS) sn -= HS;
    int si = sm * HS + sn;
    float h = hp[si];
    Gr[i] = h * cp[si];
    Gi[i] = h * sp[si];
  }
  __syncthreads();
  for (int i = threadIdx.x; i < HWS; i += 256) {
    int yy = i / HS, v = i % HS;
    float sr = 0.f, sii = 0.f;
    int t = 0;
    for (int u = 0; u < HS; ++u) {
      float gr = Gr[u * HS + v], gi = Gi[u * HS + v];
      float c = twc[t], s = tws[t];
      sr += gr * c - gi * s;
      sii += gr * s + gi * c;
      t += yy; if (t >= HS) t -= HS;
    }
    Tr[i] = sr; Ti[i] = sii;
  }
  __syncthreads();
  float* rp = rec + (size_t)img * HWS;
  const float inv = 1.f / (float)(HWS);
  for (int i = threadIdx.x; i < HWS; i += 256) {
    int yy = i / HS, xx = i % HS;
    float sr = 0.f;
    int t = 0;
    for (int v = 0; v < HS; ++v) {
      sr += Tr[yy * HS + v] * twc[t] - Ti[yy * HS + v] * tws[t];
      t += xx; if (t >= HS) t -= HS;
    }
    rp[i] = sr * inv;
  }
}

// ---------------- Kernel 6b: v = bb + wb*c0 + upsample(rec), IN-PLACE over c0
__global__ __launch_bounds__(256) void k_vmap(
    float* __restrict__ c0, const float* __restrict__ rec,
    const float* __restrict__ wb, const float* __restrict__ bb) {
  __shared__ float wblT[CR * CR];    // [c][cr]
  __shared__ float bbl[CR];
  int tid = threadIdx.x;
  for (int i = tid; i < CR * CR; i += 256) {
    int c = i / CR, cr = i % CR;
    wblT[i] = wb[cr * CR + c];
  }
  if (tid < CR) bbl[tid] = bb[tid];
  __syncthreads();
  int pix = blockIdx.x * 256 + tid;                  // over B*HW0 (exact)
  int b = pix / HW0, p = pix % HW0;
  int h = p / H0, wcol = p % H0;
  float* cb = c0 + (size_t)b * CR * HW0 + p;
  float cv[CR];
#pragma unroll
  for (int c = 0; c < CR; ++c) cv[c] = cb[(size_t)c * HW0];
  // bias + bilinear upsample (align_corners=False, clamp-to-edge)
  const float scale = (float)HS / (float)H0;
  float sy = ((float)h + 0.5f) * scale - 0.5f;
  float sx = ((float)wcol + 0.5f) * scale - 0.5f;
  float y0f = floorf(sy), x0f = floorf(sx);
  float fy = sy - y0f, fx = sx - x0f;
  int y0 = max(0, min(HS - 1, (int)y0f));
  int y1 = max(0, min(HS - 1, (int)y0f + 1));
  int x0 = max(0, min(HS - 1, (int)x0f));
  int x1 = max(0, min(HS - 1, (int)x0f + 1));
  float w00 = (1.f - fy) * (1.f - fx), w01 = (1.f - fy) * fx;
  float w10 = fy * (1.f - fx), w11 = fy * fx;
  const float* rb = rec + (size_t)b * CR * HWS;
  int i00 = y0 * HS + x0, i01 = y0 * HS + x1, i10 = y1 * HS + x0, i11 = y1 * HS + x1;
  float v[CR];
#pragma unroll
  for (int cr = 0; cr < CR; ++cr) {
    const float* rp = rb + (size_t)cr * HWS;
    v[cr] = bbl[cr] + w00 * rp[i00] + w01 * rp[i01] + w10 * rp[i10] + w11 * rp[i11];
  }
  // wb matvec
  for (int c = 0; c < CR; ++c) {
    float cvv = cv[c];
    const float4* wt = reinterpret_cast<const float4*>(&wblT[c * CR]);
#pragma unroll
    for (int q = 0; q < 8; ++q) {
      float4 wv = wt[q];
      v[q * 4 + 0] = fmaf(cvv, wv.x, v[q * 4 + 0]);
      v[q * 4 + 1] = fmaf(cvv, wv.y, v[q * 4 + 1]);
      v[q * 4 + 2] = fmaf(cvv, wv.z, v[q * 4 + 2]);
      v[q * 4 + 3] = fmaf(cvv, wv.w, v[q * 4 + 3]);
    }
  }
#pragma unroll
  for (int cr = 0; cr < CR; ++cr) cb[(size_t)cr * HW0] = v[cr];
}

// ---------------- Kernel 7: gate. thread = 2 px, co-split x4 across blocks.
#define SSPLIT 4
#define COC (CIN / SSPLIT)         // 64
__global__ __launch_bounds__(256) void k_final(
    const float* __restrict__ x, const float* __restrict__ vbuf,
    const float* __restrict__ w2, const float* __restrict__ b2,
    float* __restrict__ out) {
  __shared__ float w2l[COC * CR];    // 8 KB
  __shared__ float b2l[COC];
  int tid = threadIdx.x;
  int pg = blockIdx.x >> 2;
  int cs = blockIdx.x & 3;
  for (int i = tid; i < COC * CR; i += 256) w2l[i] = w2[cs * COC * CR + i];
  if (tid < COC) b2l[tid] = b2[cs * COC + tid];
  __syncthreads();
  int pp = (pg * 256 + tid) * 2;                    // 2 adjacent pixels
  int b = pp / HW0, p0 = pp % HW0;
  const float* vb = vbuf + (size_t)b * CR * HW0 + p0;
  float2 vv[CR];
#pragma unroll
  for (int cr = 0; cr < CR; ++cr)
    vv[cr] = *reinterpret_cast<const float2*>(vb + (size_t)cr * HW0);
  const float* xb = x + ((size_t)b * CIN + cs * COC) * HW0 + p0;
  float* ob = out + ((size_t)b * CIN + cs * COC) * HW0 + p0;
  for (int j = 0; j < COC; ++j) {
    const float4* wrow = reinterpret_cast<const float4*>(&w2l[j * CR]);
    float sa0 = 0.f, sb0 = 0.f, sa1 = 0.f, sb1 = 0.f;
#pragma unroll
    for (int q = 0; q < 8; ++q) {
      float4 w4 = wrow[q];
      float2 v0 = vv[q * 4 + 0], v1 = vv[q * 4 + 1];
      float2 v2 = vv[q * 4 + 2], v3 = vv[q * 4 + 3];
      sa0 = fmaf(v0.x, w4.x, sa0); sa1 = fmaf(v0.y, w4.x, sa1);
      sb0 = fmaf(v1.x, w4.y, sb0); sb1 = fmaf(v1.y, w4.y, sb1);
      sa0 = fmaf(v2.x, w4.z, sa0); sa1 = fmaf(v2.y, w4.z, sa1);
      sb0 = fmaf(v3.x, w4.w, sb0); sb1 = fmaf(v3.y, w4.w, sb1);
    }
    float bias = b2l[j];
    float s0 = bias + sa0 + sb0;
    float s1 = bias + sa1 + sb1;
    float2 x2 = *reinterpret_cast<const float2*>(xb + (size_t)j * HW0);
    float g0 = __builtin_amdgcn_rcpf(1.f + __expf(-s0));
    float g1 = __builtin_amdgcn_rcpf(1.f + __expf(-s1));
    *reinterpret_cast<float2*>(ob + (size_t)j * HW0) = make_float2(x2.x * g0, x2.y * g1);
  }
}

extern "C" void kernel_launch(void* const* d_in, const int* in_sizes, int n_in,
                              void* d_out, int out_size, void* d_ws, size_t ws_size,
                              hipStream_t stream) {
  const float* x    = (const float*)d_in[0];
  const float* w1   = (const float*)d_in[1];
  const float* b1   = (const float*)d_in[2];
  const float* wsw  = (const float*)d_in[3];
  const float* bs   = (const float*)d_in[4];
  const float* wb   = (const float*)d_in[5];
  const float* bb   = (const float*)d_in[6];
  const float* woff = (const float*)d_in[7];
  const float* boff = (const float*)d_in[8];
  const float* wreg = (const float*)d_in[9];
  const float* breg = (const float*)d_in[10];
  const float* w2   = (const float*)d_in[11];
  const float* b2   = (const float*)d_in[12];
  float* out = (float*)d_out;

  float* ws_f = (float*)d_ws;
  float* c0   = ws_f;
  float* c1   = c0 + (size_t)BATCH * CR * HW0;
  float* pool = c1 + (size_t)BATCH * CR * HW1;
  float* hbA  = pool + (size_t)BATCH * CR * HWS;
  float* hbB  = hbA + (size_t)BATCH * CR * HWS;
  float* cph  = hbB + (size_t)BATCH * CR * HWS;
  float* sph  = cph + (size_t)BATCH * CR * HWS;
  float* rec  = sph + (size_t)BATCH * CR * HWS;

  k_conv1x1<<<(BATCH * HW0 / 2) / 128, 128, 0, stream>>>(x, w1, b1, c0);
  k_conv3x3s2<<<(C3_THREADS + 255) / 256, 256, 0, stream>>>(c0, wsw, bs, c1);
  k_maxpool<<<(BATCH * CR * HWS + 255) / 256, 256, 0, stream>>>(c1, pool);
  k_fft<<<BATCH * CR, 256, 0, stream>>>(pool, hbA, cph, sph);
  k_dcn<<<(BATCH * HWS + 31) / 32, 256, 0, stream>>>(hbA, hbB, woff, boff, wreg, breg);
  k_dcn<<<(BATCH * HWS + 31) / 32, 256, 0, stream>>>(hbB, hbA, woff + 5184, boff + 18, wreg + 9216, breg + 32);
  k_dcn<<<(BATCH * HWS + 31) / 32, 256, 0, stream>>>(hbA, hbB, woff + 2 * 5184, boff + 36, wreg + 2 * 9216, breg + 64);
  k_ifft<<<BATCH * CR, 256, 0, stream>>>(hbB, cph, sph, rec);
  k_vmap<<<(BATCH * HW0) / 256, 256, 0, stream>>>(c0, rec, wb, bb);     // c0 -> v in-place
  k_final<<<(BATCH * HW0 / 2 / 256) * SSPLIT, 256, 0, stream>>>(x, c0, w2, b2, out);
}